// Round 4
// baseline (2253.653 us; speedup 1.0000x reference)
//
#include <hip/hip_runtime.h>

// Problem constants (from reference)
#define NN 15        // nodes == HID
#define HH 16384     // hidden channels == GRU seq len
#define G3 45        // 3*HID
#define EE 200       // edges
#define STRIDE 48    // padded GI row stride (floats); col 45 = W_lin[t]
#define CHUNK 8      // GI register double-buffer depth (steps)

typedef float f2 __attribute__((ext_vector_type(2)));

#define L2E 1.44269504f   // log2(e)

// ---------------------------------------------------------------------------
// k_prep: GCN collapse + GI precompute. Round-3 column layout (proven):
//   col g in [0,15)  : r  -> (gi_r + b_hr) * -L2E     (b_hh folded: r)
//   col g in [15,30) : z  -> (gi_z + b_hz) * -L2E     (b_hh folded: z)
//   col g in [30,45) : n  ->  gi_n         * 2*L2E    (b_hn NOT folded: it
//                                                      multiplies r in-step)
//   col 45           : W_lin[t]  (unscaled)
// ---------------------------------------------------------------------------
__global__ __launch_bounds__(256) void k_prep(
    const float* __restrict__ x, const int* __restrict__ ei,
    const float* __restrict__ Wg, const float* __restrict__ bg,
    const float* __restrict__ Wih, const float* __restrict__ bih,
    const float* __restrict__ bhh, const float* __restrict__ Wlin,
    float* __restrict__ giw)
{
    __shared__ float s_dinv[NN], s_a[NN], s_wih[G3 * NN], s_bih[G3];
    const int tid = threadIdx.x;
    for (int i = tid; i < G3 * NN; i += 256) s_wih[i] = Wih[i];
    if (tid < G3) s_bih[tid] = bih[tid];
    if (tid < NN) {
        int deg = 1;  // self loop
        for (int e = 0; e < EE; ++e) deg += (ei[EE + e] == tid) ? 1 : 0;
        s_dinv[tid] = rsqrtf((float)deg);
    }
    __syncthreads();
    if (tid < NN) {
        const float di = s_dinv[tid];
        float acc = di * di * x[tid];  // self loop
        for (int e = 0; e < EE; ++e) {
            if (ei[EE + e] == tid) {
                const int s = ei[e];
                acc += s_dinv[s] * di * x[s];
            }
        }
        s_a[tid] = acc;
    }
    __syncthreads();
    const int t = blockIdx.x * 256 + tid;
    if (t >= HH) return;
    const float wg = Wg[t], bb = bg[t];
    float h1[NN];
    #pragma unroll
    for (int n = 0; n < NN; ++n) h1[n] = fmaxf(0.0f, fmaf(s_a[n], wg, bb));
    float* row = giw + t * STRIDE;
    #pragma unroll 9
    for (int g = 0; g < G3; ++g) {
        float a = s_bih[g];
        #pragma unroll
        for (int n = 0; n < NN; ++n) a = fmaf(h1[n], s_wih[g * NN + n], a);
        if (g < 30) row[g] = (a + bhh[g]) * -L2E;     // r, z (b_hh folded)
        else        row[g] = a * (2.0f * L2E);        // n
    }
    row[45] = Wlin[t];
}

// ---------------------------------------------------------------------------
// k_scan: sequential GRU, one wave, NO cross-lane ops in the recurrence.
// Lane g in [0,15): owns gate-triple g. Three dots per step:
//   stream1/col g    -> r   (w1 = Whh row g     * -L2E)
//   stream2/col 30+g -> n   (w2 = Whh row 30+g  * 2*L2E; b_hn as accum init)
//   stream3/col 15+g -> z   (w3 = Whh row 15+g  * -L2E)
// Lane 15: stream1 reads col 45 = W_lin[t], broadcast via readlane(.,15).
// h broadcast to SGPRs via 15 v_readlane per step (proven structure).
// ---------------------------------------------------------------------------
__device__ __forceinline__ float bcast_f(float v, int lane) {
    return __builtin_bit_cast(float,
        __builtin_amdgcn_readlane(__builtin_bit_cast(int, v), lane));
}

__device__ __forceinline__ void gru_step(
    float gi1, float gi2, float gi3,
    const f2 (&w1)[8], const f2 (&w2)[8], const f2 (&w3)[8], float b2,
    f2 (&hs)[8], float& vh, float& acc)
{
    // three dual-accumulator packed dots (v_pk_fma_f32)
    f2 a0 = {gi1, 0.0f}, a1 = {0.0f, 0.0f};   // r (gi folded as init)
    f2 c0 = {b2,  0.0f}, c1 = {0.0f, 0.0f};   // n (b_hn as init)
    f2 d0 = {gi3, 0.0f}, d1 = {0.0f, 0.0f};   // z (gi folded as init)
    #pragma unroll
    for (int k = 0; k < 8; k += 2) {
        a0 += hs[k]     * w1[k];
        a1 += hs[k + 1] * w1[k + 1];
        c0 += hs[k]     * w2[k];
        c1 += hs[k + 1] * w2[k + 1];
        d0 += hs[k]     * w3[k];
        d1 += hs[k + 1] * w3[k + 1];
    }
    const f2 av = a0 + a1, cv = c0 + c1, dv = d0 + d1;
    const float gh1 = av.x + av.y;   // -L2E*(gi_r + b_hr + W_r.h)
    const float gh2 = cv.x + cv.y;   // 2L2E*(b_hn + W_n.h)
    const float gh3 = dv.x + dv.y;   // -L2E*(gi_z + b_hz + W_z.h)
    const float sv = __builtin_amdgcn_rcpf(1.0f + __builtin_amdgcn_exp2f(gh1)); // r
    const float zv = __builtin_amdgcn_rcpf(1.0f + __builtin_amdgcn_exp2f(gh3)); // z
    const float x2 = fmaf(sv, gh2, gi2);       // 2L2E*(i_n + r*(W_n.h + b_hn))
    const float tv = fmaf(-2.0f,
        __builtin_amdgcn_rcpf(1.0f + __builtin_amdgcn_exp2f(x2)), 1.0f);        // n
    const float omz = 1.0f - zv;               // ready before tv
    const float pre = zv * vh;                 // ready before tv
    const float hnew = fmaf(tv, omz, pre);     // 1 op after tanh
    vh = hnew;
    const float wl = bcast_f(gi1, 15);         // W_lin[t] from lane 15
    acc = fmaf(hnew, wl, acc);
    #pragma unroll
    for (int k = 0; k < 7; ++k) {
        hs[k].x = bcast_f(hnew, 2 * k);
        hs[k].y = bcast_f(hnew, 2 * k + 1);
    }
    hs[7].x = bcast_f(hnew, 14);
    hs[7].y = 0.0f;
}

__global__ __launch_bounds__(64, 1) void k_scan(
    const float* __restrict__ Whh, const float* __restrict__ bhh,
    const float* __restrict__ blin, const float* __restrict__ giw,
    float* __restrict__ out)
{
    const int lane = threadIdx.x;
    const int g  = (lane < 15) ? lane : 14;          // clamped gate index
    const int r1 = g, r2 = 30 + g, r3 = 15 + g;
    f2 w1[8], w2[8], w3[8];
    #pragma unroll
    for (int k = 0; k < 8; ++k) {
        const int i0 = 2 * k, i1 = 2 * k + 1;
        const bool ok = (i1 < NN);
        w1[k].x = Whh[r1 * NN + i0] * -L2E;
        w1[k].y = ok ? Whh[r1 * NN + i1] * -L2E : 0.0f;
        w2[k].x = Whh[r2 * NN + i0] * (2.0f * L2E);
        w2[k].y = ok ? Whh[r2 * NN + i1] * (2.0f * L2E) : 0.0f;
        w3[k].x = Whh[r3 * NN + i0] * -L2E;
        w3[k].y = ok ? Whh[r3 * NN + i1] * -L2E : 0.0f;
    }
    const float b2 = bhh[r2] * (2.0f * L2E);         // b_hn (scaled)

    const int c1 = (lane < 15) ? lane : ((lane == 15) ? 45 : 44);
    const int c2 = (lane < 15) ? (30 + lane) : 44;
    const int c3 = (lane < 15) ? (15 + lane) : 44;

    f2 hs[8];
    #pragma unroll
    for (int k = 0; k < 8; ++k) hs[k] = (f2){0.0f, 0.0f};
    float vh = 0.0f, acc = 0.0f;

    float A1[CHUNK], A2[CHUNK], A3[CHUNK], B1[CHUNK], B2[CHUNK], B3[CHUNK];
    const float* p1 = giw + c1;
    const float* p2 = giw + c2;
    const float* p3 = giw + c3;
    #pragma unroll
    for (int s = 0; s < CHUNK; ++s) {
        A1[s] = p1[s * STRIDE]; A2[s] = p2[s * STRIDE]; A3[s] = p3[s * STRIDE];
    }

    for (int it = 0; it < HH / (2 * CHUNK); ++it) {
        // prefetch next chunk into B while computing A
        #pragma unroll
        for (int s = 0; s < CHUNK; ++s) {
            B1[s] = p1[(CHUNK + s) * STRIDE];
            B2[s] = p2[(CHUNK + s) * STRIDE];
            B3[s] = p3[(CHUNK + s) * STRIDE];
        }
        #pragma unroll
        for (int s = 0; s < CHUNK; ++s)
            gru_step(A1[s], A2[s], A3[s], w1, w2, w3, b2, hs, vh, acc);
        #pragma unroll
        for (int s = 0; s < CHUNK; ++s) {
            A1[s] = p1[(2 * CHUNK + s) * STRIDE];
            A2[s] = p2[(2 * CHUNK + s) * STRIDE];
            A3[s] = p3[(2 * CHUNK + s) * STRIDE];
        }
        #pragma unroll
        for (int s = 0; s < CHUNK; ++s)
            gru_step(B1[s], B2[s], B3[s], w1, w2, w3, b2, hs, vh, acc);
        p1 += 2 * CHUNK * STRIDE;
        p2 += 2 * CHUNK * STRIDE;
        p3 += 2 * CHUNK * STRIDE;
    }
    if (lane < NN) out[lane] = acc + blin[0];
}

// ---------------------------------------------------------------------------
extern "C" void kernel_launch(void* const* d_in, const int* in_sizes, int n_in,
                              void* d_out, int out_size, void* d_ws, size_t ws_size,
                              hipStream_t stream)
{
    const float* x    = (const float*)d_in[0];
    const int*   ei   = (const int*)  d_in[1];
    const float* Wg   = (const float*)d_in[2];
    const float* bg   = (const float*)d_in[3];
    const float* Wih  = (const float*)d_in[4];
    const float* Whh  = (const float*)d_in[5];
    const float* bih  = (const float*)d_in[6];
    const float* bhh  = (const float*)d_in[7];
    const float* Wlin = (const float*)d_in[8];
    const float* blin = (const float*)d_in[9];
    float* out = (float*)d_out;
    float* giw = (float*)d_ws;   // needs (HH + 2*CHUNK)*STRIDE*4 ~= 3.15 MB

    k_prep<<<HH / 256, 256, 0, stream>>>(x, ei, Wg, bg, Wih, bih, bhh, Wlin, giw);
    k_scan<<<1, 64, 0, stream>>>(Whh, bhh, blin, giw, out);
}